// Round 1
// baseline (602.558 us; speedup 1.0000x reference)
//
#include <hip/hip_runtime.h>
#include <math.h>

#define N_B 16
#define N_C 256
#define HH 128
#define WW 128
#define PLANE (HH * WW)                    // 16384 floats per (b,c) plane
#define PLANES_PER_TENSOR (N_B * N_C)      // 4096

// ---------------------------------------------------------------------------
// Kernel 1: 64x64-window maxpool over each 128x128 plane -> 2x2 outputs.
// Grid: 2 * 16 * 256 = 8192 blocks, 256 threads each.
// Wave w (0..3) of a block owns quadrant (oh=w>>1, ow=w&1).
// Each lane: 16 float4 loads (64 floats), local max, then wave shfl-xor max.
// Every input float is read exactly once, 16B/lane coalesced.
// ---------------------------------------------------------------------------
__global__ __launch_bounds__(256) void pool_kernel(
    const float* __restrict__ predS, const float* __restrict__ predT,
    const int* __restrict__ feat_ind, float* __restrict__ pooled)
{
    const int bid    = blockIdx.x;          // 0..8191
    const int tensor = bid >> 12;           // 0 = S, 1 = T
    const int bc     = bid & 4095;          // b*256 + c
    const float* src = tensor ? predT : predS;
    const long long base =
        (long long)feat_ind[0] * ((long long)PLANES_PER_TENSOR * PLANE) +
        (long long)bc * PLANE;
    const float4* __restrict__ p = (const float4*)(src + base);

    const int tid  = threadIdx.x;
    const int wv   = tid >> 6;              // quadrant index 0..3
    const int lane = tid & 63;
    const int oh   = wv >> 1;
    const int ow   = wv & 1;

    // Plane = 128 rows x 32 float4. Quadrant = rows oh*64.., col4 ow*16..
    float m = -INFINITY;
#pragma unroll
    for (int i = 0; i < 16; ++i) {
        const int f  = i * 64 + lane;       // 0..1023 float4 within quadrant
        const int r  = f >> 4;              // 0..63 row in window
        const int c4 = f & 15;              // 0..15 float4 col in window
        const float4 v = p[(oh * 64 + r) * 32 + ow * 16 + c4];
        m = fmaxf(m, fmaxf(fmaxf(v.x, v.y), fmaxf(v.z, v.w)));
    }
#pragma unroll
    for (int s = 1; s < 64; s <<= 1)
        m = fmaxf(m, __shfl_xor(m, s));

    if (lane == 0) {
        // pooled layout: [tensor][b][c][m], m = oh*2 + ow (row-major spatial)
        pooled[bid * 4 + (oh * 2 + ow)] = m;
    }
}

// ---------------------------------------------------------------------------
// Block-wide sum reduction of K per-thread values (256 threads = 4 waves).
// Results broadcast in res[0..K-1].
// ---------------------------------------------------------------------------
template <int K>
__device__ __forceinline__ void block_reduce(float* v, float lds[4][20],
                                             float* res, int lane, int wv)
{
#pragma unroll
    for (int k = 0; k < K; ++k) {
        float x = v[k];
#pragma unroll
        for (int s = 1; s < 64; s <<= 1) x += __shfl_xor(x, s);
        if (lane == 0) lds[wv][k] = x;
    }
    __syncthreads();
    if (wv == 0 && lane < K)
        res[lane] = lds[0][lane] + lds[1][lane] + lds[2][lane] + lds[3][lane];
    __syncthreads();
}

// ---------------------------------------------------------------------------
// Kernel 2: normalize pooled feats over channels, per-batch gram (4x4),
// squared error sum, scale by 1/(M*M)/B = 1/256. Single block, 256 threads
// (thread = channel). Negligible runtime vs kernel 1.
// ---------------------------------------------------------------------------
__global__ __launch_bounds__(256) void sim_kernel(
    const float* __restrict__ pooled, float* __restrict__ out)
{
    __shared__ float lds[4][20];
    __shared__ float res[20];
    const int tid  = threadIdx.x;           // channel
    const int lane = tid & 63;
    const int wv   = tid >> 6;
    const float4* __restrict__ ps = (const float4*)pooled;  // [2][16][256] float4

    float total = 0.f;
    for (int b = 0; b < N_B; ++b) {
        const float4 sv = ps[b * N_C + tid];
        const float4 tv = ps[PLANES_PER_TENSOR + b * N_C + tid];
        float s[4] = {sv.x, sv.y, sv.z, sv.w};
        float t[4] = {tv.x, tv.y, tv.z, tv.w};

        // Phase 1: per-spatial-location sum of squares over channels (norms)
        float v[8];
#pragma unroll
        for (int m = 0; m < 4; ++m) { v[m] = s[m] * s[m]; v[4 + m] = t[m] * t[m]; }
        block_reduce<8>(v, lds, res, lane, wv);

        float ns[4], nt[4];
#pragma unroll
        for (int m = 0; m < 4; ++m) {
            ns[m] = sqrtf(res[m])     + 1e-8f;
            nt[m] = sqrtf(res[4 + m]) + 1e-8f;
        }
#pragma unroll
        for (int m = 0; m < 4; ++m) { s[m] /= ns[m]; t[m] /= nt[m]; }

        // Phase 2: symmetric gram products (10 unique each for S and T)
        float w[20];
        int idx = 0;
#pragma unroll
        for (int m = 0; m < 4; ++m)
#pragma unroll
            for (int n = m; n < 4; ++n) {
                w[idx]      = s[m] * s[n];
                w[10 + idx] = t[m] * t[n];
                ++idx;
            }
        block_reduce<20>(w, lds, res, lane, wv);

        if (tid == 0) {
            float err = 0.f;
            int k = 0;
#pragma unroll
            for (int m = 0; m < 4; ++m)
#pragma unroll
                for (int n = m; n < 4; ++n) {
                    const float d = res[10 + k] - res[k];
                    err += (m == n ? 1.f : 2.f) * d * d;  // off-diag counted twice
                    ++k;
                }
            total += err;
        }
        // next iteration's block_reduce syncs before overwriting lds/res
    }

    if (tid == 0)
        out[0] = total * (1.0f / 256.0f);   // / (M*M) / B = /16/16
}

extern "C" void kernel_launch(void* const* d_in, const int* in_sizes, int n_in,
                              void* d_out, int out_size, void* d_ws, size_t ws_size,
                              hipStream_t stream)
{
    const float* predS = (const float*)d_in[0];
    const float* predT = (const float*)d_in[1];
    const int*   find  = (const int*)d_in[2];
    float* pooled = (float*)d_ws;           // 2*16*256*4 floats = 128 KB
    float* outp   = (float*)d_out;

    pool_kernel<<<dim3(2 * PLANES_PER_TENSOR), dim3(256), 0, stream>>>(
        predS, predT, find, pooled);
    sim_kernel<<<dim3(1), dim3(256), 0, stream>>>(pooled, outp);
}

// Round 3
// 573.730 us; speedup vs baseline: 1.0502x; 1.0502x over previous
//
#include <hip/hip_runtime.h>
#include <math.h>

#define N_B 16
#define N_C 256
#define HH 128
#define WW 128
#define PLANE (HH * WW)                    // 16384 floats per (b,c) plane
#define PLANES_PER_TENSOR (N_B * N_C)      // 4096

typedef float f4 __attribute__((ext_vector_type(4)));  // native vector: OK for nontemporal builtin

// ---------------------------------------------------------------------------
// Kernel 1: 64x64-window maxpool over each 128x128 plane -> 2x2 outputs.
// Grid: 2 * 16 * 256 = 8192 blocks, 256 threads each.
// Wave w (0..3) of a block owns quadrant (oh=w>>1, ow=w&1).
// Each lane: 16 nontemporal float4 loads (read-once data — don't pollute
// L2/LLC), local max, then wave shfl-xor max.
// ---------------------------------------------------------------------------
__global__ __launch_bounds__(256) void pool_kernel(
    const float* __restrict__ predS, const float* __restrict__ predT,
    const int* __restrict__ feat_ind, float* __restrict__ pooled)
{
    const int bid    = blockIdx.x;          // 0..8191
    const int tensor = bid >> 12;           // 0 = S, 1 = T
    const int bc     = bid & 4095;          // b*256 + c
    const float* src = tensor ? predT : predS;
    const long long base =
        (long long)feat_ind[0] * ((long long)PLANES_PER_TENSOR * PLANE) +
        (long long)bc * PLANE;
    const f4* __restrict__ p = (const f4*)(src + base);

    const int tid  = threadIdx.x;
    const int wv   = tid >> 6;              // quadrant index 0..3
    const int lane = tid & 63;
    const int oh   = wv >> 1;
    const int ow   = wv & 1;

    // Plane = 128 rows x 32 float4. Quadrant = rows oh*64.., col4 ow*16..
    // Issue all 16 independent loads first (compiler keeps them in flight),
    // then reduce.
    f4 v[16];
#pragma unroll
    for (int i = 0; i < 16; ++i) {
        const int f  = i * 64 + lane;       // 0..1023 float4 within quadrant
        const int r  = f >> 4;              // 0..63 row in window
        const int c4 = f & 15;              // 0..15 float4 col in window
        v[i] = __builtin_nontemporal_load(&p[(oh * 64 + r) * 32 + ow * 16 + c4]);
    }
    float m = -INFINITY;
#pragma unroll
    for (int i = 0; i < 16; ++i)
        m = fmaxf(m, fmaxf(fmaxf(v[i].x, v[i].y), fmaxf(v[i].z, v[i].w)));

#pragma unroll
    for (int s = 1; s < 64; s <<= 1)
        m = fmaxf(m, __shfl_xor(m, s));

    if (lane == 0) {
        // pooled layout: [tensor][b][c][m], m = oh*2 + ow (row-major spatial)
        pooled[bid * 4 + (oh * 2 + ow)] = m;
    }
}

// ---------------------------------------------------------------------------
// Block-wide sum reduction of K per-thread values (256 threads = 4 waves).
// Results broadcast in res[0..K-1].
// ---------------------------------------------------------------------------
template <int K>
__device__ __forceinline__ void block_reduce(float* v, float lds[4][20],
                                             float* res, int lane, int wv)
{
#pragma unroll
    for (int k = 0; k < K; ++k) {
        float x = v[k];
#pragma unroll
        for (int s = 1; s < 64; s <<= 1) x += __shfl_xor(x, s);
        if (lane == 0) lds[wv][k] = x;
    }
    __syncthreads();
    if (wv == 0 && lane < K)
        res[lane] = lds[0][lane] + lds[1][lane] + lds[2][lane] + lds[3][lane];
    __syncthreads();
}

// ---------------------------------------------------------------------------
// Kernel 2: normalize pooled feats over channels, per-batch gram (4x4),
// squared error sum, scale by 1/(M*M)/B = 1/256. Single block, 256 threads
// (thread = channel). Negligible runtime vs kernel 1.
// ---------------------------------------------------------------------------
__global__ __launch_bounds__(256) void sim_kernel(
    const float* __restrict__ pooled, float* __restrict__ out)
{
    __shared__ float lds[4][20];
    __shared__ float res[20];
    const int tid  = threadIdx.x;           // channel
    const int lane = tid & 63;
    const int wv   = tid >> 6;
    const float4* __restrict__ ps = (const float4*)pooled;  // [2][16][256] float4

    float total = 0.f;
    for (int b = 0; b < N_B; ++b) {
        const float4 sv = ps[b * N_C + tid];
        const float4 tv = ps[PLANES_PER_TENSOR + b * N_C + tid];
        float s[4] = {sv.x, sv.y, sv.z, sv.w};
        float t[4] = {tv.x, tv.y, tv.z, tv.w};

        // Phase 1: per-spatial-location sum of squares over channels (norms)
        float v[8];
#pragma unroll
        for (int m = 0; m < 4; ++m) { v[m] = s[m] * s[m]; v[4 + m] = t[m] * t[m]; }
        block_reduce<8>(v, lds, res, lane, wv);

        float ns[4], nt[4];
#pragma unroll
        for (int m = 0; m < 4; ++m) {
            ns[m] = sqrtf(res[m])     + 1e-8f;
            nt[m] = sqrtf(res[4 + m]) + 1e-8f;
        }
#pragma unroll
        for (int m = 0; m < 4; ++m) { s[m] /= ns[m]; t[m] /= nt[m]; }

        // Phase 2: symmetric gram products (10 unique each for S and T)
        float w[20];
        int idx = 0;
#pragma unroll
        for (int m = 0; m < 4; ++m)
#pragma unroll
            for (int n = m; n < 4; ++n) {
                w[idx]      = s[m] * s[n];
                w[10 + idx] = t[m] * t[n];
                ++idx;
            }
        block_reduce<20>(w, lds, res, lane, wv);

        if (tid == 0) {
            float err = 0.f;
            int k = 0;
#pragma unroll
            for (int m = 0; m < 4; ++m)
#pragma unroll
                for (int n = m; n < 4; ++n) {
                    const float d = res[10 + k] - res[k];
                    err += (m == n ? 1.f : 2.f) * d * d;  // off-diag counted twice
                    ++k;
                }
            total += err;
        }
        // next iteration's block_reduce syncs before overwriting lds/res
    }

    if (tid == 0)
        out[0] = total * (1.0f / 256.0f);   // / (M*M) / B = /16/16
}

extern "C" void kernel_launch(void* const* d_in, const int* in_sizes, int n_in,
                              void* d_out, int out_size, void* d_ws, size_t ws_size,
                              hipStream_t stream)
{
    const float* predS = (const float*)d_in[0];
    const float* predT = (const float*)d_in[1];
    const int*   find  = (const int*)d_in[2];
    float* pooled = (float*)d_ws;           // 2*16*256*4 floats = 128 KB
    float* outp   = (float*)d_out;

    pool_kernel<<<dim3(2 * PLANES_PER_TENSOR), dim3(256), 0, stream>>>(
        predS, predT, find, pooled);
    sim_kernel<<<dim3(1), dim3(256), 0, stream>>>(pooled, outp);
}